// Round 21
// baseline (89.505 us; speedup 1.0000x reference)
//
#include <hip/hip_runtime.h>

typedef int int32x4 __attribute__((ext_vector_type(4)));

#define B_ 32
#define C_ 256
#define H_ 56
#define W_ 56

static constexpr float QSCALE = 255.0f / 8.0f;   // 31.875 (exact); x<1 -> n in [0,32]
static constexpr float D1 = 8.0f / 255.0f;

// Xq global layout: [b][cig 0..15][h 0..57][w 0..57][ci16] -- per-cig plane is linear.
#define PLANE 53824          // 58*58*16
#define BSTR  861184         // 16 * PLANE
static constexpr size_t XQ_BYTES = (size_t)B_ * BSTR;             // 27,541,504
static constexpr size_t XQ_SPACE = XQ_BYTES + 32768;
static constexpr size_t WT_SPACE = 38ull * 16384;                 // 36 steps + 2 pad
static constexpr size_t WS_NEED = XQ_SPACE + WT_SPACE + 2048;

#define XROWB 4096           // LDS stride per ci-group: 4 rows x 64 slots x 16B
#define XBUFB (4 * XROWB)    // 16,384 B (single buffer)

__device__ __forceinline__ void gload_lds16(const void* g, void* l) {
  __builtin_amdgcn_global_load_lds((const __attribute__((address_space(1))) unsigned int*)g,
                                   (__attribute__((address_space(3))) unsigned int*)l,
                                   16, 0, 0);
}

// ---------------- Kernel 1: FUSED prep — input quant+transpose AND weight quant ------------
// blocks [0,1792): quantize x row (b = blk/56, h = blk%56) -> Xq [b][cig][h][w][ci16]
// blocks [1792,2048): per-c_out weight absmax + 36 chunk-local error-feedback chains -> Wt
// Wt layout (linear): Wt[(step*256 + co)*64 + (ci & 63)], step = (ci>>6)*9 + pos.
__global__ __launch_bounds__(256) void prep_all(const float* __restrict__ x,
                                                const float* __restrict__ w,
                                                char* __restrict__ Xq,
                                                char* __restrict__ Wt,
                                                float* __restrict__ oscale) {
  __shared__ __align__(16) char smem[16384];
  const int tid = threadIdx.x;

  if (blockIdx.x < 1792) {
    // ---------------- input quantize + transpose ----------------
    char* T8 = smem;                            // [w 0..57][c], row pad to 272 (15,776 B)
    const int h = blockIdx.x % 56;              // 0..55 -> padded row h+1
    const int b = blockIdx.x / 56;
    const int c = tid;

    T8[0 * 272 + c] = 0;                        // side borders w=0 and w=57
    T8[57 * 272 + c] = 0;

    const float4* src = (const float4*)(x + (((size_t)b * C_ + c) * H_ + h) * W_);
#pragma unroll
    for (int i = 0; i < 14; ++i) {
      float4 v = src[i];
      float vals[4] = {v.x, v.y, v.z, v.w};
      const int w0 = i * 4;
#pragma unroll
      for (int j = 0; j < 4; ++j) {
        int n = (int)rintf(vals[j] * QSCALE);
        n = n < 0 ? 0 : (n > 255 ? 255 : n);
        T8[(w0 + j + 1) * 272 + c] = (char)n;
      }
    }
    __syncthreads();

    char* Xb = Xq + (size_t)b * BSTR;
#pragma unroll
    for (int p = 0; p < 4; ++p) {
      if (tid < 232) {
        const int wd = tid % 58;
        const int cig = p * 4 + tid / 58;
        *(int4*)(Xb + (size_t)cig * PLANE + (h + 1) * 928 + wd * 16) =
            *(const int4*)&T8[wd * 272 + cig * 16];
      }
    }

    if (h == 0 || h == 55) {
      const int hb = (h == 0) ? 0 : 57;
      const int4 z = {0, 0, 0, 0};
      for (int i = tid; i < 928; i += 256) {
        const int wd = i % 58;
        const int cig = i / 58;
        *(int4*)(Xb + (size_t)cig * PLANE + hb * 928 + wd * 16) = z;
      }
    }
  } else {
    // ---------------- weight quantize (one block per c_out) ----------------
    float* wf = (float*)smem;                   // 2304 floats (9216 B)
    char* Wq = smem + 9216;                     // 2304 B, [chunk=cc*9+p][ci&63]
    float* red = (float*)(smem + 11520);        // 4 floats
    float* sbc = (float*)(smem + 11536);        // 1 float
    const int co = blockIdx.x - 1792;

    const float4* src = (const float4*)(w + (size_t)co * 2304);
    float m = 0.f;
    for (int i = tid; i < 576; i += 256) {
      float4 v = src[i];
      *(float4*)&wf[i * 4] = v;
      m = fmaxf(fmaxf(fabsf(v.x), fabsf(v.y)), fmaxf(fmaxf(fabsf(v.z), fabsf(v.w)), m));
    }

#pragma unroll
    for (int off = 32; off; off >>= 1) m = fmaxf(m, __shfl_down(m, off));
    if ((tid & 63) == 0) red[tid >> 6] = m;
    __syncthreads();
    if (tid == 0) {
      m = fmaxf(fmaxf(red[0], red[1]), fmaxf(red[2], red[3]));
      m = fmaxf(m, 1e-20f);
      *sbc = m;
      oscale[co] = (m / 127.f) * D1;
    }
    __syncthreads();

    // 36 parallel chunk-local error-feedback chains: lane = cq*9 + p, chain over 64 ci
    if (tid < 36) {
      const int p = tid % 9;
      const int cq = tid / 9;                   // ci chunk 0..3
      const float s = *sbc / 127.f;
      const float inv = 1.f / s;
      float carry = 0.f;
      for (int k = 0; k < 64; ++k) {
        const int ci = cq * 64 + k;
        float t = wf[ci * 9 + p] + carry;
        float qf = rintf(t * inv);
        qf = fminf(fmaxf(qf, -128.f), 127.f);
        carry = t - qf * s;
        Wq[(cq * 9 + p) * 64 + k] = (char)(int)qf;
      }
    }
    __syncthreads();

    if (tid < 144) {
      const int chunk = tid >> 2;               // step = cc*9 + p
      const int g = tid & 3;                    // 16B group
      int4 v = *(const int4*)&Wq[chunk * 64 + (g << 4)];
      *(int4*)(Wt + ((size_t)(chunk * 256 + co)) * 64 + (g << 4)) = v;
    }
  }
}

// ---------------- Kernel 2: implicit-GEMM conv, i8 MFMA 16x16x64 ---------------------------
// 4 waves. BM=128 co (2 m-frags/wave), BN=112 (2 rows, 7 n-frags). 36 steps of K=64.
// Grid 1792 = 2 co-halves x 28 by x 32 b. W: global->named-reg depth-2.
// X: SINGLE LDS buffer [hi][row*64 + w]. MSTEP: ALL 7 ds_reads issue before the 14 MFMAs,
// NO setprio (it fenced cross-step load hoisting; this loop is lockstep so T5 can't pay).
__global__ __launch_bounds__(256, 4) void conv_mfma_i8(const char* __restrict__ Xq,
                                                       const char* __restrict__ Wt,
                                                       const float* __restrict__ oscale,
                                                       float* __restrict__ out) {
  __shared__ __align__(16) char Xl[XBUFB];      // 16,384 B
  const int tid = threadIdx.x;
  const int wid = tid >> 6, lane = tid & 63;
  const int col = lane & 15, hi = lane >> 4;

  // XCD-aware bijective swizzle: 1792 = 8 XCDs x 224; co-half pairs stay adjacent
  const int l = blockIdx.x;
  const int wk = (l & 7) * 224 + (l >> 3);
  const int mh = wk & 1;
  const int rest = wk >> 1;          // 0..895
  const int by = rest % 28;
  const int b = rest / 28;
  const int h0 = 2 * by;

  int banf[7];
#pragma unroll
  for (int nf = 0; nf < 7; ++nf) {
    const int n_out = nf * 16 + col;
    const int r = n_out >= 56 ? 1 : 0;
    banf[nf] = hi * XROWB + (r * 64 + (n_out - r * 56)) * 16;
  }

  int32x4 acc[2][7];
#pragma unroll
  for (int mf = 0; mf < 2; ++mf)
#pragma unroll
    for (int nf = 0; nf < 7; ++nf) acc[mf][nf] = (int32x4){0, 0, 0, 0};

  const char* Xqb = Xq + (size_t)b * BSTR + h0 * 928;
  const char* wg = Wt + (size_t)((mh * 128 + wid * 32 + col) * 64 + hi * 16);

  int32x4 Wc0, Wc1, Wn0, Wn1;

  // ---- staging: 4 passes; pass p, wave wid stages (hi,row) pair p*4+wid, lanes 0..57 ----
#define STAGE_X(xsrc_)                                                                   \
  {                                                                                      \
    _Pragma("unroll") for (int p = 0; p < 4; ++p) {                                      \
      const int pair = p * 4 + wid;                                                      \
      const int hq = pair >> 2;                                                          \
      const int rr = pair & 3;                                                           \
      if (lane < 58)                                                                     \
        gload_lds16((xsrc_) + (size_t)hq * PLANE + rr * 928 + lane * 16,                 \
                    Xl + hq * XROWB + rr * 1024 + lane * 16);                            \
    }                                                                                    \
  }

  STAGE_X(Xqb)
  Wc0 = *(const int32x4*)(wg);
  Wc1 = *(const int32x4*)(wg + 1024);
  Wn0 = *(const int32x4*)(wg + 16384);
  Wn1 = *(const int32x4*)(wg + 16384 + 1024);
  __syncthreads();

#define MSTEP(POS, PROW16)                                                               \
  {                                                                                      \
    int32x4 bb[7];                                                                       \
    _Pragma("unroll") for (int nf = 0; nf < 7; ++nf)                                     \
        bb[nf] = *(const int32x4*)(Xl + banf[nf] + (PROW16));                            \
    _Pragma("unroll") for (int nf = 0; nf < 7; ++nf) {                                   \
      acc[0][nf] = __builtin_amdgcn_mfma_i32_16x16x64_i8(Wc0, bb[nf], acc[0][nf], 0, 0, 0); \
      acc[1][nf] = __builtin_amdgcn_mfma_i32_16x16x64_i8(Wc1, bb[nf], acc[1][nf], 0, 0, 0); \
    }                                                                                    \
    Wc0 = Wn0; Wc1 = Wn1;                                                                \
    Wn0 = *(const int32x4*)(wgcc + ((POS) + 2) * 16384);                                 \
    Wn1 = *(const int32x4*)(wgcc + ((POS) + 2) * 16384 + 1024);                          \
  }

  const char* wgcc = wg;
#pragma unroll 1
  for (int cc = 0; cc < 4; ++cc) {
    // pos offsets: kh*1024 + kw*16
    MSTEP(0, 0)
    MSTEP(1, 16)
    MSTEP(2, 32)
    MSTEP(3, 1024)
    MSTEP(4, 1040)
    MSTEP(5, 1056)
    MSTEP(6, 2048)
    MSTEP(7, 2064)
    MSTEP(8, 2080)
    if (cc < 3) {
      __syncthreads();                          // all waves done reading Xl
      STAGE_X(Xqb + (size_t)(4 * (cc + 1)) * PLANE)
      __syncthreads();                          // vmcnt(0) drain: staged data visible
    }
    wgcc += 9 * 16384;
  }
#undef MSTEP
#undef STAGE_X

  // ---- epilogue: out = acc * oscale[co]; C row = co (hi*4 + r4), col = spatial ----
#pragma unroll
  for (int mf = 0; mf < 2; ++mf) {
    const int cbase = mh * 128 + wid * 32 + mf * 16 + hi * 4;
    const float4 os = *(const float4*)(oscale + cbase);
#pragma unroll
    for (int nf = 0; nf < 7; ++nf) {
      const int n_out = nf * 16 + col;
      const int r = n_out >= 56 ? 1 : 0;
      const int hrow = h0 + r;
      const int wcol = n_out - r * 56;
      float* o = out + ((((size_t)b * 256 + cbase) * 56 + hrow) * 56 + wcol);
      o[0 * 3136] = (float)acc[mf][nf][0] * os.x;
      o[1 * 3136] = (float)acc[mf][nf][1] * os.y;
      o[2 * 3136] = (float)acc[mf][nf][2] * os.z;
      o[3 * 3136] = (float)acc[mf][nf][3] * os.w;
    }
  }
}

// ---------------- Fallback: naive direct conv (if ws too small) ----------------------------
__global__ void conv_naive(const float* __restrict__ x, const float* __restrict__ w,
                           float* __restrict__ out, int total) {
  int idx = blockIdx.x * 256 + threadIdx.x;
  if (idx >= total) return;
  const int wc = idx % 56;
  int t = idx / 56;
  const int hr = t % 56; t /= 56;
  const int co = t % 256;
  const int b = t / 256;
  float acc = 0.f;
  for (int ci = 0; ci < 256; ++ci) {
    const float* xb = x + (((size_t)b * 256 + ci) * 56) * 56;
    const float* wb = w + ((size_t)co * 256 + ci) * 9;
#pragma unroll
    for (int kh = 0; kh < 3; ++kh) {
      const int hh = hr + kh - 1;
      if (hh < 0 || hh >= 56) continue;
#pragma unroll
      for (int kw = 0; kw < 3; ++kw) {
        const int ww = wc + kw - 1;
        if (ww < 0 || ww >= 56) continue;
        const float q = rintf(xb[hh * 56 + ww] * QSCALE) * D1;
        acc += q * wb[kh * 3 + kw];
      }
    }
  }
  out[idx] = acc;
}

extern "C" void kernel_launch(void* const* d_in, const int* in_sizes, int n_in,
                              void* d_out, int out_size, void* d_ws, size_t ws_size,
                              hipStream_t stream) {
  (void)in_sizes; (void)n_in; (void)out_size;
  const float* x = (const float*)d_in[0];
  const float* w = (const float*)d_in[1];
  float* out = (float*)d_out;

  if (ws_size < WS_NEED) {
    const int total = B_ * C_ * H_ * W_;
    conv_naive<<<(total + 255) / 256, 256, 0, stream>>>(x, w, out, total);
    return;
  }

  char* Xq = (char*)d_ws;
  char* Wt = (char*)d_ws + XQ_SPACE;
  float* oscale = (float*)((char*)d_ws + XQ_SPACE + WT_SPACE);

  prep_all<<<dim3(2048), 256, 0, stream>>>(x, w, Xq, Wt, oscale);
  conv_mfma_i8<<<dim3(1792), 256, 0, stream>>>(Xq, Wt, oscale, out);
}

// Round 22
// 84.798 us; speedup vs baseline: 1.0555x; 1.0555x over previous
//
#include <hip/hip_runtime.h>

typedef int int32x4 __attribute__((ext_vector_type(4)));

#define B_ 32
#define C_ 256
#define H_ 56
#define W_ 56

static constexpr float QSCALE = 255.0f / 8.0f;   // 31.875 (exact); x<1 -> n in [0,32]
static constexpr float D1 = 8.0f / 255.0f;

// Xq global layout: [b][cig 0..15][h 0..57][w 0..57][ci16] -- per-cig plane is linear.
#define PLANE 53824          // 58*58*16
#define BSTR  861184         // 16 * PLANE
static constexpr size_t XQ_BYTES = (size_t)B_ * BSTR;             // 27,541,504
static constexpr size_t XQ_SPACE = XQ_BYTES + 32768;
static constexpr size_t WT_SPACE = 38ull * 16384;                 // 36 steps + 2 pad
static constexpr size_t WS_NEED = XQ_SPACE + WT_SPACE + 2048;

#define XROWB 4096           // LDS stride per ci-group: 4 rows x 64 slots x 16B
                             // row stride 1024B ≡ 0 mod 32 banks -> wrap-free phases
#define XBUFB (4 * XROWB)    // 16,384 B (single buffer)

__device__ __forceinline__ void gload_lds16(const void* g, void* l) {
  __builtin_amdgcn_global_load_lds((const __attribute__((address_space(1))) unsigned int*)g,
                                   (__attribute__((address_space(3))) unsigned int*)l,
                                   16, 0, 0);
}

// ---------------- Kernel 1: FUSED prep — input quant+transpose AND weight quant ------------
// blocks [0,1792): quantize x row (b = blk/56, h = blk%56) -> Xq [b][cig][h][w][ci16]
// blocks [1792,2048): per-c_out weight absmax + 36 chunk-local error-feedback chains -> Wt
// Wt layout (linear): Wt[(step*256 + co)*64 + (ci & 63)], step = (ci>>6)*9 + pos.
__global__ __launch_bounds__(256) void prep_all(const float* __restrict__ x,
                                                const float* __restrict__ w,
                                                char* __restrict__ Xq,
                                                char* __restrict__ Wt,
                                                float* __restrict__ oscale) {
  __shared__ __align__(16) char smem[16384];
  const int tid = threadIdx.x;

  if (blockIdx.x < 1792) {
    // ---------------- input quantize + transpose ----------------
    char* T8 = smem;                            // [w 0..57][c], row pad to 272 (15,776 B)
    const int h = blockIdx.x % 56;              // 0..55 -> padded row h+1
    const int b = blockIdx.x / 56;
    const int c = tid;

    T8[0 * 272 + c] = 0;                        // side borders w=0 and w=57
    T8[57 * 272 + c] = 0;

    const float4* src = (const float4*)(x + (((size_t)b * C_ + c) * H_ + h) * W_);
#pragma unroll
    for (int i = 0; i < 14; ++i) {
      float4 v = src[i];
      float vals[4] = {v.x, v.y, v.z, v.w};
      const int w0 = i * 4;
#pragma unroll
      for (int j = 0; j < 4; ++j) {
        int n = (int)rintf(vals[j] * QSCALE);
        n = n < 0 ? 0 : (n > 255 ? 255 : n);
        T8[(w0 + j + 1) * 272 + c] = (char)n;
      }
    }
    __syncthreads();

    char* Xb = Xq + (size_t)b * BSTR;
#pragma unroll
    for (int p = 0; p < 4; ++p) {
      if (tid < 232) {
        const int wd = tid % 58;
        const int cig = p * 4 + tid / 58;
        *(int4*)(Xb + (size_t)cig * PLANE + (h + 1) * 928 + wd * 16) =
            *(const int4*)&T8[wd * 272 + cig * 16];
      }
    }

    if (h == 0 || h == 55) {
      const int hb = (h == 0) ? 0 : 57;
      const int4 z = {0, 0, 0, 0};
      for (int i = tid; i < 928; i += 256) {
        const int wd = i % 58;
        const int cig = i / 58;
        *(int4*)(Xb + (size_t)cig * PLANE + hb * 928 + wd * 16) = z;
      }
    }
  } else {
    // ---------------- weight quantize (one block per c_out) ----------------
    float* wf = (float*)smem;                   // 2304 floats (9216 B)
    char* Wq = smem + 9216;                     // 2304 B, [chunk=cc*9+p][ci&63]
    float* red = (float*)(smem + 11520);        // 4 floats
    float* sbc = (float*)(smem + 11536);        // 1 float
    const int co = blockIdx.x - 1792;

    const float4* src = (const float4*)(w + (size_t)co * 2304);
    float m = 0.f;
    for (int i = tid; i < 576; i += 256) {
      float4 v = src[i];
      *(float4*)&wf[i * 4] = v;
      m = fmaxf(fmaxf(fabsf(v.x), fabsf(v.y)), fmaxf(fmaxf(fabsf(v.z), fabsf(v.w)), m));
    }

#pragma unroll
    for (int off = 32; off; off >>= 1) m = fmaxf(m, __shfl_down(m, off));
    if ((tid & 63) == 0) red[tid >> 6] = m;
    __syncthreads();
    if (tid == 0) {
      m = fmaxf(fmaxf(red[0], red[1]), fmaxf(red[2], red[3]));
      m = fmaxf(m, 1e-20f);
      *sbc = m;
      oscale[co] = (m / 127.f) * D1;
    }
    __syncthreads();

    // 36 parallel chunk-local error-feedback chains: lane = cq*9 + p, chain over 64 ci
    if (tid < 36) {
      const int p = tid % 9;
      const int cq = tid / 9;                   // ci chunk 0..3
      const float s = *sbc / 127.f;
      const float inv = 1.f / s;
      float carry = 0.f;
      for (int k = 0; k < 64; ++k) {
        const int ci = cq * 64 + k;
        float t = wf[ci * 9 + p] + carry;
        float qf = rintf(t * inv);
        qf = fminf(fmaxf(qf, -128.f), 127.f);
        carry = t - qf * s;
        Wq[(cq * 9 + p) * 64 + k] = (char)(int)qf;
      }
    }
    __syncthreads();

    if (tid < 144) {
      const int chunk = tid >> 2;               // step = cc*9 + p
      const int g = tid & 3;                    // 16B group
      int4 v = *(const int4*)&Wq[chunk * 64 + (g << 4)];
      *(int4*)(Wt + ((size_t)(chunk * 256 + co)) * 64 + (g << 4)) = v;
    }
  }
}

// ---------------- Kernel 2: implicit-GEMM conv, i8 MFMA 16x16x64 ---------------------------
// 4 waves. BM=128 co (2 m-frags/wave), BN=112 (2 rows, 7 n-frags). 36 steps of K=64.
// Grid 1792 = 2 co-halves x 28 by x 32 b. W: global->named-reg depth-2.
// X: SINGLE LDS buffer [hi][row*64 + w]: 1024B row stride (≡0 mod 32 banks) kills the
// row-wrap bank conflicts. Staging: per-(hi,row) wave-level linear global_load_lds.
__global__ __launch_bounds__(256, 4) void conv_mfma_i8(const char* __restrict__ Xq,
                                                       const char* __restrict__ Wt,
                                                       const float* __restrict__ oscale,
                                                       float* __restrict__ out) {
  __shared__ __align__(16) char Xl[XBUFB];      // 16,384 B
  const int tid = threadIdx.x;
  const int wid = tid >> 6, lane = tid & 63;
  const int col = lane & 15, hi = lane >> 4;

  // XCD-aware bijective swizzle: 1792 = 8 XCDs x 224; co-half pairs stay adjacent
  const int l = blockIdx.x;
  const int wk = (l & 7) * 224 + (l >> 3);
  const int mh = wk & 1;
  const int rest = wk >> 1;          // 0..895
  const int by = rest % 28;
  const int b = rest / 28;
  const int h0 = 2 * by;

  int banf[7];
#pragma unroll
  for (int nf = 0; nf < 7; ++nf) {
    const int n_out = nf * 16 + col;
    const int r = n_out >= 56 ? 1 : 0;
    banf[nf] = hi * XROWB + (r * 64 + (n_out - r * 56)) * 16;
  }

  int32x4 acc[2][7];
#pragma unroll
  for (int mf = 0; mf < 2; ++mf)
#pragma unroll
    for (int nf = 0; nf < 7; ++nf) acc[mf][nf] = (int32x4){0, 0, 0, 0};

  const char* Xqb = Xq + (size_t)b * BSTR + h0 * 928;
  const char* wg = Wt + (size_t)((mh * 128 + wid * 32 + col) * 64 + hi * 16);

  int32x4 Wc0, Wc1, Wn0, Wn1;

  // ---- staging: 4 passes; pass p, wave wid stages (hi,row) pair p*4+wid, lanes 0..57 ----
#define STAGE_X(xsrc_)                                                                   \
  {                                                                                      \
    _Pragma("unroll") for (int p = 0; p < 4; ++p) {                                      \
      const int pair = p * 4 + wid;                                                      \
      const int hq = pair >> 2;                                                          \
      const int rr = pair & 3;                                                           \
      if (lane < 58)                                                                     \
        gload_lds16((xsrc_) + (size_t)hq * PLANE + rr * 928 + lane * 16,                 \
                    Xl + hq * XROWB + rr * 1024 + lane * 16);                            \
    }                                                                                    \
  }

  STAGE_X(Xqb)
  Wc0 = *(const int32x4*)(wg);
  Wc1 = *(const int32x4*)(wg + 1024);
  Wn0 = *(const int32x4*)(wg + 16384);
  Wn1 = *(const int32x4*)(wg + 16384 + 1024);
  __syncthreads();

#define MSTEP(POS, PROW16)                                                               \
  {                                                                                      \
    __builtin_amdgcn_s_setprio(1);                                                       \
    _Pragma("unroll") for (int nf = 0; nf < 7; ++nf) {                                   \
      int32x4 bb = *(const int32x4*)(Xl + banf[nf] + (PROW16));                          \
      acc[0][nf] = __builtin_amdgcn_mfma_i32_16x16x64_i8(Wc0, bb, acc[0][nf], 0, 0, 0);  \
      acc[1][nf] = __builtin_amdgcn_mfma_i32_16x16x64_i8(Wc1, bb, acc[1][nf], 0, 0, 0);  \
    }                                                                                    \
    __builtin_amdgcn_s_setprio(0);                                                       \
    Wc0 = Wn0; Wc1 = Wn1;                                                                \
    Wn0 = *(const int32x4*)(wgcc + ((POS) + 2) * 16384);                                 \
    Wn1 = *(const int32x4*)(wgcc + ((POS) + 2) * 16384 + 1024);                          \
  }

  const char* wgcc = wg;
#pragma unroll 1
  for (int cc = 0; cc < 4; ++cc) {
    // pos offsets: kh*1024 + kw*16
    MSTEP(0, 0)
    MSTEP(1, 16)
    MSTEP(2, 32)
    MSTEP(3, 1024)
    MSTEP(4, 1040)
    MSTEP(5, 1056)
    MSTEP(6, 2048)
    MSTEP(7, 2064)
    MSTEP(8, 2080)
    if (cc < 3) {
      __syncthreads();                          // all waves done reading Xl
      STAGE_X(Xqb + (size_t)(4 * (cc + 1)) * PLANE)
      __syncthreads();                          // vmcnt(0) drain: staged data visible
    }
    wgcc += 9 * 16384;
  }
#undef MSTEP
#undef STAGE_X

  // ---- epilogue: out = acc * oscale[co]; C row = co (hi*4 + r4), col = spatial ----
#pragma unroll
  for (int mf = 0; mf < 2; ++mf) {
    const int cbase = mh * 128 + wid * 32 + mf * 16 + hi * 4;
    const float4 os = *(const float4*)(oscale + cbase);
#pragma unroll
    for (int nf = 0; nf < 7; ++nf) {
      const int n_out = nf * 16 + col;
      const int r = n_out >= 56 ? 1 : 0;
      const int hrow = h0 + r;
      const int wcol = n_out - r * 56;
      float* o = out + ((((size_t)b * 256 + cbase) * 56 + hrow) * 56 + wcol);
      o[0 * 3136] = (float)acc[mf][nf][0] * os.x;
      o[1 * 3136] = (float)acc[mf][nf][1] * os.y;
      o[2 * 3136] = (float)acc[mf][nf][2] * os.z;
      o[3 * 3136] = (float)acc[mf][nf][3] * os.w;
    }
  }
}

// ---------------- Fallback: naive direct conv (if ws too small) ----------------------------
__global__ void conv_naive(const float* __restrict__ x, const float* __restrict__ w,
                           float* __restrict__ out, int total) {
  int idx = blockIdx.x * 256 + threadIdx.x;
  if (idx >= total) return;
  const int wc = idx % 56;
  int t = idx / 56;
  const int hr = t % 56; t /= 56;
  const int co = t % 256;
  const int b = t / 256;
  float acc = 0.f;
  for (int ci = 0; ci < 256; ++ci) {
    const float* xb = x + (((size_t)b * 256 + ci) * 56) * 56;
    const float* wb = w + ((size_t)co * 256 + ci) * 9;
#pragma unroll
    for (int kh = 0; kh < 3; ++kh) {
      const int hh = hr + kh - 1;
      if (hh < 0 || hh >= 56) continue;
#pragma unroll
      for (int kw = 0; kw < 3; ++kw) {
        const int ww = wc + kw - 1;
        if (ww < 0 || ww >= 56) continue;
        const float q = rintf(xb[hh * 56 + ww] * QSCALE) * D1;
        acc += q * wb[kh * 3 + kw];
      }
    }
  }
  out[idx] = acc;
}

extern "C" void kernel_launch(void* const* d_in, const int* in_sizes, int n_in,
                              void* d_out, int out_size, void* d_ws, size_t ws_size,
                              hipStream_t stream) {
  (void)in_sizes; (void)n_in; (void)out_size;
  const float* x = (const float*)d_in[0];
  const float* w = (const float*)d_in[1];
  float* out = (float*)d_out;

  if (ws_size < WS_NEED) {
    const int total = B_ * C_ * H_ * W_;
    conv_naive<<<(total + 255) / 256, 256, 0, stream>>>(x, w, out, total);
    return;
  }

  char* Xq = (char*)d_ws;
  char* Wt = (char*)d_ws + XQ_SPACE;
  float* oscale = (float*)((char*)d_ws + XQ_SPACE + WT_SPACE);

  prep_all<<<dim3(2048), 256, 0, stream>>>(x, w, Xq, Wt, oscale);
  conv_mfma_i8<<<dim3(1792), 256, 0, stream>>>(Xq, Wt, oscale, out);
}